// Round 5
// baseline (2493.030 us; speedup 1.0000x reference)
//
#include <hip/hip_runtime.h>
#include <cmath>

#define T_STEPS 512
#define BATCH   64
#define ISZ     512
#define HSZ     512
#define EXN     32768   // u64 words per ring slot (64 batches x 512)

// ---------------------------------------------------------------------------
// Phase 1 (fp32): xw[m][n] = sum_k x[m][k] * w_ih[n][k]   (32768 x 512 x 512)
// fp32 VALU SGEMM (no fp32 MFMA on CDNA4). UNCHANGED (proven rounds 3-4).
// ---------------------------------------------------------------------------
__global__ __launch_bounds__(256) void rnn_xw_f32(const float* __restrict__ x,
                                                  const float* __restrict__ wih,
                                                  float* __restrict__ out) {
    __shared__ float As[32][68];
    __shared__ float Bs[32][68];

    const int tid = threadIdx.x;
    const int n0  = blockIdx.x * 64;
    const int m0  = blockIdx.y * 64;
    const int r0  = (tid & 15) * 4;
    const int c0  = (tid >> 4) * 4;
    const int sr  = tid >> 2;
    const int sc  = (tid & 3) * 8;

    float acc[4][4] = {};

    const float* ap = x   + (size_t)(m0 + sr) * ISZ + sc;
    const float* bp = wih + (size_t)(n0 + sr) * ISZ + sc;

    for (int k0 = 0; k0 < ISZ; k0 += 32) {
        const float4 a0 = *(const float4*)(ap + k0);
        const float4 a1 = *(const float4*)(ap + k0 + 4);
        const float4 b0 = *(const float4*)(bp + k0);
        const float4 b1 = *(const float4*)(bp + k0 + 4);
        __syncthreads();
        As[sc + 0][sr] = a0.x; As[sc + 1][sr] = a0.y;
        As[sc + 2][sr] = a0.z; As[sc + 3][sr] = a0.w;
        As[sc + 4][sr] = a1.x; As[sc + 5][sr] = a1.y;
        As[sc + 6][sr] = a1.z; As[sc + 7][sr] = a1.w;
        Bs[sc + 0][sr] = b0.x; Bs[sc + 1][sr] = b0.y;
        Bs[sc + 2][sr] = b0.z; Bs[sc + 3][sr] = b0.w;
        Bs[sc + 4][sr] = b1.x; Bs[sc + 5][sr] = b1.y;
        Bs[sc + 6][sr] = b1.z; Bs[sc + 7][sr] = b1.w;
        __syncthreads();

        #pragma unroll
        for (int k = 0; k < 32; ++k) {
            const float4 av = *(const float4*)&As[k][r0];
            const float4 bv = *(const float4*)&Bs[k][c0];
            const float a[4] = {av.x, av.y, av.z, av.w};
            const float b[4] = {bv.x, bv.y, bv.z, bv.w};
            #pragma unroll
            for (int i = 0; i < 4; ++i)
                #pragma unroll
                for (int j = 0; j < 4; ++j)
                    acc[i][j] = fmaf(a[i], b[j], acc[i][j]);
        }
    }

    #pragma unroll
    for (int i = 0; i < 4; ++i) {
        float4 v; v.x = acc[i][0]; v.y = acc[i][1]; v.z = acc[i][2]; v.w = acc[i][3];
        *(float4*)(out + (size_t)(m0 + r0 + i) * HSZ + n0 + c0) = v;
    }
}

// ---------------------------------------------------------------------------
// Tagged-word exchange (proven): one atomic u64 = {tag = t+1 (hi32), h bits
// (lo32)}. Per-location atomicity only. Depth-2 ring safe: every WG consumes
// every peer's words each step (all-to-all), so inter-WG lag <= 1 step.
// ---------------------------------------------------------------------------
__device__ __forceinline__ void ex_store(unsigned long long* w, float h, unsigned tag) {
    union { float f; unsigned u; } c; c.f = h;
    const unsigned long long v = ((unsigned long long)tag << 32) | (unsigned long long)c.u;
    __hip_atomic_store(w, v, __ATOMIC_RELAXED, __HIP_MEMORY_SCOPE_AGENT);
}

// ---------------------------------------------------------------------------
// Phase 2: 256 WGs (32 batch-pairs x 8 neuron-slices), 1 WG/CU.
// Per thread: 8 outputs x 16 k x 1 batch; W_hh micro-panel = 128 floats
// PINNED in VGPRs via opaque asm (round-4 counter showed VGPR=88: compiler
// was NOT keeping weights resident). In-wave shfl reduction (no red LDS, no
// 2nd barrier). hl double-buffered by step parity -> 1 barrier/step.
// hl chunk stride padded 4->5 float4 to spread bank-quad starts.
// ---------------------------------------------------------------------------
__global__ __launch_bounds__(512, 2) void rnn_rec(const float* __restrict__ whh,
                                                  float* __restrict__ out,
                                                  unsigned long long* __restrict__ ex) {
    __shared__ float4 hl4[660];            // [2 slots][2 batches][32 ks][5 f4]
    float* hl = (float*)hl4;

    const int tid  = threadIdx.x;
    const int p    = blockIdx.x >> 3;      // batch pair 0..31
    const int g    = blockIdx.x & 7;       // neuron slice 0..7
    const int j0   = g * 64;
    const int lane = tid & 63;
    const int wv   = tid >> 6;             // wave 0..7: owns j = j0+wv*8 .. +7
    const int b    = lane & 1;             // batch within pair
    const int ks   = lane >> 1;            // k-segment 0..31 (16 k each)

    // ---- W_hh micro-panel: rows j0+wv*8+jx, cols [ks*16, ks*16+16) ----
    float4 wq[32];                          // [jx][i] -> 128 floats
    {
        const float* wr = whh + (size_t)(j0 + wv * 8) * HSZ + ks * 16;
        #pragma unroll
        for (int jx = 0; jx < 8; ++jx)
            #pragma unroll
            for (int i = 0; i < 4; ++i)
                wq[jx * 4 + i] = *(const float4*)(wr + (size_t)jx * HSZ + 4 * i);
    }
    // pin in arch VGPRs: opaque to rematerialization
    #pragma unroll
    for (int n = 0; n < 32; ++n)
        asm volatile("" : "+v"(wq[n].x), "+v"(wq[n].y), "+v"(wq[n].z), "+v"(wq[n].w));

    // poll words for this thread: batch 0/1, element k = tid
    unsigned long long* exb = ex + (size_t)(2 * p) * 512 + tid;
    // hl scalar write offset (within one batch region), element k = tid
    const int fo = (((tid >> 4) * 5 + ((tid >> 2) & 3)) << 2) + (tid & 3);

    for (int t = 0; t < T_STEPS; ++t) {
        // prefetch own xw (phase-1 output; this thread overwrites it below)
        float4 xwa, xwb;
        if (lane < 2) {
            const float* xp = out + ((size_t)t * BATCH + 2 * p + lane) * HSZ + j0 + wv * 8;
            xwa = *(const float4*)xp;
            xwb = *(const float4*)(xp + 4);
        }

        float p8[8] = {0.f, 0.f, 0.f, 0.f, 0.f, 0.f, 0.f, 0.f};
        if (t > 0) {
            const int    s    = (t - 1) & 1;
            const size_t soff = (size_t)s * EXN;
            unsigned long long v0 = __hip_atomic_load(exb + soff, __ATOMIC_RELAXED,
                                                      __HIP_MEMORY_SCOPE_AGENT);
            unsigned long long v1 = __hip_atomic_load(exb + soff + 512, __ATOMIC_RELAXED,
                                                      __HIP_MEMORY_SCOPE_AGENT);
            while ((unsigned)(v0 >> 32) != (unsigned)t ||
                   (unsigned)(v1 >> 32) != (unsigned)t) {
                __builtin_amdgcn_s_sleep(1);
                v0 = __hip_atomic_load(exb + soff, __ATOMIC_RELAXED,
                                       __HIP_MEMORY_SCOPE_AGENT);
                v1 = __hip_atomic_load(exb + soff + 512, __ATOMIC_RELAXED,
                                       __HIP_MEMORY_SCOPE_AGENT);
            }
            union { unsigned u; float f; } c0, c1;
            c0.u = (unsigned)v0; c1.u = (unsigned)v1;
            hl[s * 1320 + fo]       = c0.f;   // batch 0
            hl[s * 1320 + 660 + fo] = c1.f;   // batch 1
            __syncthreads();                                    // B1 (only barrier)

            // dot: 8 outputs x 16 k, weights in pinned regs
            const float4* hb = hl4 + s * 330 + b * 165 + ks * 5;
            #pragma unroll
            for (int i = 0; i < 4; ++i) {
                const float4 h4 = hb[i];
                #pragma unroll
                for (int jx = 0; jx < 8; ++jx) {
                    const float4 wv4 = wq[jx * 4 + i];
                    p8[jx] = fmaf(wv4.x, h4.x, p8[jx]);
                    p8[jx] = fmaf(wv4.y, h4.y, p8[jx]);
                    p8[jx] = fmaf(wv4.z, h4.z, p8[jx]);
                    p8[jx] = fmaf(wv4.w, h4.w, p8[jx]);
                }
            }
            // in-wave fold over ks (lane bits 1..5); lanes 0/1 keep b=0/1 sums
            #pragma unroll
            for (int d = 2; d <= 32; d <<= 1)
                #pragma unroll
                for (int jx = 0; jx < 8; ++jx)
                    p8[jx] += __shfl_xor(p8[jx], d, 64);
        }

        if (lane < 2) {
            float hv[8];
            #pragma unroll
            for (int n = 0; n < 8; ++n) {
                const float a2 = p8[n] + ((n < 4) ? (&xwa.x)[n] : (&xwb.x)[n - 4]);
                const float e  = __expf(2.f * a2);      // tanh = 1 - 2/(e+1)
                hv[n] = 1.f - 2.f / (e + 1.f);
            }
            float* op = out + ((size_t)t * BATCH + 2 * p + lane) * HSZ + j0 + wv * 8;
            float4 o0, o1;
            o0.x = hv[0]; o0.y = hv[1]; o0.z = hv[2]; o0.w = hv[3];
            o1.x = hv[4]; o1.y = hv[5]; o1.z = hv[6]; o1.w = hv[7];
            *(float4*)op       = o0;
            *(float4*)(op + 4) = o1;
            if (t < T_STEPS - 1) {
                unsigned long long* ep = ex + (size_t)(t & 1) * EXN
                                       + (size_t)(2 * p + lane) * 512 + j0 + wv * 8;
                #pragma unroll
                for (int n = 0; n < 8; ++n)
                    ex_store(ep + n, hv[n], (unsigned)(t + 1));
            } else {
                float* lp = out + (size_t)T_STEPS * BATCH * HSZ
                          + (size_t)(2 * p + lane) * HSZ + j0 + wv * 8;
                *(float4*)lp       = o0;
                *(float4*)(lp + 4) = o1;
            }
        }
        // no trailing barrier: hl double-buffered by parity; B1(t+1) ordering
        // prevents buffer reuse before all waves' dot(t) reads complete.
    }
}

// ---------------------------------------------------------------------------
extern "C" void kernel_launch(void* const* d_in, const int* in_sizes, int n_in,
                              void* d_out, int out_size, void* d_ws, size_t ws_size,
                              hipStream_t stream) {
    (void)in_sizes; (void)n_in; (void)out_size; (void)ws_size;
    const float* x    = (const float*)d_in[0];   // (512,64,512)
    const float* wih  = (const float*)d_in[1];   // (512,512)
    const float* whh  = (const float*)d_in[2];   // (512,512)
    float*       out  = (float*)d_out;           // h_all (T,B,H) ++ h_last (B,H)
    unsigned long long* ex = (unsigned long long*)d_ws;   // 2*EXN u64 = 512 KB

    // zero exchange region (harness re-poisons d_ws to 0xAA each launch;
    // tag 0 matches no step since tags are 1..511)
    (void)hipMemsetAsync(d_ws, 0, 2 * EXN * sizeof(unsigned long long), stream);

    hipLaunchKernelGGL(rnn_xw_f32, dim3(8, 512), dim3(256), 0, stream, x, wih, out);
    hipLaunchKernelGGL(rnn_rec, dim3(256), dim3(512), 0, stream, whh, out, ex);
}